// Round 1
// baseline (5329.381 us; speedup 1.0000x reference)
//
#include <hip/hip_runtime.h>

// TextDecoder: 2-layer LSTM, B=64, H=1024, V=10000, T=32 (31 computed steps).
// Round 2: single persistent kernel (256 blocks x 256 threads, 1 block/CU,
// guaranteed co-resident) running the whole time loop with manual device-scope
// grid barriers. 4 barriers/step instead of 6 kernel launches/step:
//   P1 cell0 (token select via per-block reduce of argmax candidates)
//   P2 layer-1 GEMMs (x@Wih1, h2@Whh1), KS=2
//   P3 cell1
//   P4 logits GEMM full-K (writes out+bias+argmax candidates directly,
//      killing the old sumarg kernel)  ||  L0 GEMM for step t+1 (independent)
// Weight conversion (fp32 -> fp16 hi + lo*2048 split) and state init are
// phase 0 of the same kernel. Host side: 1 memset (barrier) + 1 launch.

#define HDIM 1024
#define BDIM 64
#define VDIM 10000
#define VPAD 10048   // 157 * 64
#define TDIM 32
#define NB   256     // persistent blocks == CU count; all co-resident

typedef _Float16 f16;
typedef _Float16 f16x8 __attribute__((ext_vector_type(8)));
typedef _Float16 f16x4 __attribute__((ext_vector_type(4)));
typedef float f32x4 __attribute__((ext_vector_type(4)));

// ---- workspace layout (bytes). Total 101,056,512 <= proven ws_size (>=101,450,752).
#define WS_C1    0              // 64x1024 f32
#define WS_C2    262144
#define WS_H1H   524288         // 64x1024 f16 each
#define WS_H1L   655360
#define WS_H2H   786432
#define WS_H2L   917504
#define WS_PRE0  1048576        // 4 slabs x 64x4096 f32 (layer0 h-gemm partials)
#define WS_PRE1  5242880        // 4 slabs x 64x4096 f32 (layer1 partials: z*2+q)
#define WS_CAND  9437184        // 64 rows x 157 tiles x u64 argmax candidates
#define WS_BAR   9517568        // 256 B grid-barrier state (memset to 0 per call)
#define WS_WB    9568256        // converted weights
#define WSQ      8388608        // 4096x1024 f16
#define WVO      20578304       // 10048x1024 f16

__device__ __forceinline__ float sigmoidf_(float x) {
    return 1.0f / (1.0f + expf(-x));
}

// Sense-reversing grid barrier: cnt at bar[0], generation at bar[32] (128B apart).
// Agent-scope acq/rel atomics + threadfence handle cross-XCD L2 visibility
// (same primitive cooperative-groups grid.sync uses).
__device__ __forceinline__ void gridbar(int* bar) {
    __syncthreads();
    if (threadIdx.x == 0) {
        __threadfence();
        int g = __hip_atomic_load(bar + 32, __ATOMIC_RELAXED, __HIP_MEMORY_SCOPE_AGENT);
        int a = __hip_atomic_fetch_add(bar, 1, __ATOMIC_ACQ_REL, __HIP_MEMORY_SCOPE_AGENT);
        if (a == NB - 1) {
            __hip_atomic_store(bar, 0, __ATOMIC_RELAXED, __HIP_MEMORY_SCOPE_AGENT);
            __hip_atomic_fetch_add(bar + 32, 1, __ATOMIC_RELEASE, __HIP_MEMORY_SCOPE_AGENT);
        } else {
            while (__hip_atomic_load(bar + 32, __ATOMIC_ACQUIRE, __HIP_MEMORY_SCOPE_AGENT) == g)
                __builtin_amdgcn_s_sleep(4);
        }
    }
    __syncthreads();
}

// ------------------------------------------------------------------
// Split-fp16 MFMA fragment compute for one 64x64 tile (2x2 waves of 32x32).
// A rows arow..arow+31 (per wave), W rows wrow..wrow+31, k in [kbase, kbase+klen).
// Verified layout from round-1 kernel: C row = m0 + rt*16 + quad*4 + r,
// col = n0 + ct*16 + lm.  x = hi + lo/2048; 3 MFMA paths (hh, hl, lh).
// ------------------------------------------------------------------
__device__ __forceinline__ void gemm_frag(
    const f16* __restrict__ Ah, const f16* __restrict__ Al,
    const f16* __restrict__ Wh, const f16* __restrict__ Wl,
    int arow, int wrow, int kbase, int klen,
    f32x4 acc[2][2], f32x4 accL[2][2])
{
    const int lane = threadIdx.x & 63;
    const int lm = lane & 15, quad = lane >> 4;
    const f16* a_h = Ah + (size_t)(arow + lm) * HDIM + kbase + quad * 8;
    const f16* a_l = Al + (size_t)(arow + lm) * HDIM + kbase + quad * 8;
    const f16* b_h = Wh + (size_t)(wrow + lm) * HDIM + kbase + quad * 8;
    const f16* b_l = Wl + (size_t)(wrow + lm) * HDIM + kbase + quad * 8;
    #pragma unroll 4
    for (int ko = 0; ko < klen; ko += 32) {
        f16x8 ah0 = *(const f16x8*)(a_h + ko);
        f16x8 ah1 = *(const f16x8*)(a_h + 16 * HDIM + ko);
        f16x8 al0 = *(const f16x8*)(a_l + ko);
        f16x8 al1 = *(const f16x8*)(a_l + 16 * HDIM + ko);
        f16x8 bh0 = *(const f16x8*)(b_h + ko);
        f16x8 bh1 = *(const f16x8*)(b_h + 16 * HDIM + ko);
        f16x8 bl0 = *(const f16x8*)(b_l + ko);
        f16x8 bl1 = *(const f16x8*)(b_l + 16 * HDIM + ko);

        acc[0][0] = __builtin_amdgcn_mfma_f32_16x16x32_f16(ah0, bh0, acc[0][0], 0, 0, 0);
        acc[0][1] = __builtin_amdgcn_mfma_f32_16x16x32_f16(ah0, bh1, acc[0][1], 0, 0, 0);
        acc[1][0] = __builtin_amdgcn_mfma_f32_16x16x32_f16(ah1, bh0, acc[1][0], 0, 0, 0);
        acc[1][1] = __builtin_amdgcn_mfma_f32_16x16x32_f16(ah1, bh1, acc[1][1], 0, 0, 0);

        accL[0][0] = __builtin_amdgcn_mfma_f32_16x16x32_f16(ah0, bl0, accL[0][0], 0, 0, 0);
        accL[0][1] = __builtin_amdgcn_mfma_f32_16x16x32_f16(ah0, bl1, accL[0][1], 0, 0, 0);
        accL[1][0] = __builtin_amdgcn_mfma_f32_16x16x32_f16(ah1, bl0, accL[1][0], 0, 0, 0);
        accL[1][1] = __builtin_amdgcn_mfma_f32_16x16x32_f16(ah1, bl1, accL[1][1], 0, 0, 0);

        accL[0][0] = __builtin_amdgcn_mfma_f32_16x16x32_f16(al0, bh0, accL[0][0], 0, 0, 0);
        accL[0][1] = __builtin_amdgcn_mfma_f32_16x16x32_f16(al0, bh1, accL[0][1], 0, 0, 0);
        accL[1][0] = __builtin_amdgcn_mfma_f32_16x16x32_f16(al1, bh0, accL[1][0], 0, 0, 0);
        accL[1][1] = __builtin_amdgcn_mfma_f32_16x16x32_f16(al1, bh1, accL[1][1], 0, 0, 0);
    }
}

// 64x64 tile -> fp32 store into a [64 x ldd] slab.
__device__ __forceinline__ void gemm_store(
    const f16* __restrict__ Ah, const f16* __restrict__ Al,
    const f16* __restrict__ Wh, const f16* __restrict__ Wl,
    int n0, int kbase, int klen, float* __restrict__ dst, int ldd)
{
    const int tid = threadIdx.x;
    const int wave = tid >> 6, wr = wave >> 1, wc = wave & 1;
    const int lane = tid & 63, lm = lane & 15, quad = lane >> 4;
    f32x4 acc[2][2] = {};
    f32x4 accL[2][2] = {};
    gemm_frag(Ah, Al, Wh, Wl, wr * 32, n0 + wc * 32, kbase, klen, acc, accL);
    #pragma unroll
    for (int rt = 0; rt < 2; rt++)
        #pragma unroll
        for (int ct = 0; ct < 2; ct++)
            #pragma unroll
            for (int r = 0; r < 4; r++) {
                int row = wr * 32 + rt * 16 + quad * 4 + r;
                int col = n0 + wc * 32 + ct * 16 + lm;
                dst[(size_t)row * ldd + col] =
                    acc[rt][ct][r] + accL[rt][ct][r] * (1.0f / 2048.0f);
            }
}

// fp32 -> (hi fp16, lo fp16*2048) for a 4096x1024 square, grid-strided.
__device__ __forceinline__ void convsq(const float* __restrict__ src,
                                       f16* __restrict__ hi, f16* __restrict__ lo,
                                       int gtid)
{
    const float4* s4 = (const float4*)src;
    f16x4* h4 = (f16x4*)hi;
    f16x4* l4 = (f16x4*)lo;
    for (int i = gtid; i < 4096 * HDIM / 4; i += NB * 256) {
        float4 v = s4[i];
        f16 a = (f16)v.x, b = (f16)v.y, c = (f16)v.z, d = (f16)v.w;
        f16x4 H = {a, b, c, d};
        f16x4 L = {(f16)((v.x - (float)a) * 2048.0f), (f16)((v.y - (float)b) * 2048.0f),
                   (f16)((v.z - (float)c) * 2048.0f), (f16)((v.w - (float)d) * 2048.0f)};
        h4[i] = H;
        l4[i] = L;
    }
}

__global__ __launch_bounds__(256) void decode_all(
    const float* __restrict__ hidden, const float* __restrict__ cellin,
    const int* __restrict__ captions, const int* __restrict__ tfmask,
    const float* __restrict__ Wih0, const float* __restrict__ Whh0,
    const float* __restrict__ bih0, const float* __restrict__ bhh0,
    const float* __restrict__ Wih1, const float* __restrict__ Whh1,
    const float* __restrict__ bih1, const float* __restrict__ bhh1,
    const float* __restrict__ Wout, const float* __restrict__ bout,
    float* __restrict__ out, char* __restrict__ wsb)
{
    const int tid = threadIdx.x, bid = blockIdx.x;
    const int gtid = (bid << 8) + tid;

    float* c1 = (float*)(wsb + WS_C1);
    float* c2 = (float*)(wsb + WS_C2);
    f16* h1h = (f16*)(wsb + WS_H1H);
    f16* h1l = (f16*)(wsb + WS_H1L);
    f16* h2h = (f16*)(wsb + WS_H2H);
    f16* h2l = (f16*)(wsb + WS_H2L);
    float* pre0 = (float*)(wsb + WS_PRE0);
    float* pre1 = (float*)(wsb + WS_PRE1);
    unsigned long long* cand = (unsigned long long*)(wsb + WS_CAND);
    int* bar = (int*)(wsb + WS_BAR);
    f16* Whh0h = (f16*)(wsb + WS_WB);
    f16* Whh0l = (f16*)(wsb + WS_WB + (size_t)WSQ);
    f16* Wih1h = (f16*)(wsb + WS_WB + 2 * (size_t)WSQ);
    f16* Wih1l = (f16*)(wsb + WS_WB + 3 * (size_t)WSQ);
    f16* Whh1h = (f16*)(wsb + WS_WB + 4 * (size_t)WSQ);
    f16* Whh1l = (f16*)(wsb + WS_WB + 5 * (size_t)WSQ);
    f16* Wouth = (f16*)(wsb + WS_WB + 6 * (size_t)WSQ);
    f16* Woutl = (f16*)(wsb + WS_WB + 6 * (size_t)WSQ + (size_t)WVO);

    // ---------------- phase 0: weight conversion + state init ----------------
    convsq(Whh0, Whh0h, Whh0l, gtid);
    convsq(Wih1, Wih1h, Wih1l, gtid);
    convsq(Whh1, Whh1h, Whh1l, gtid);
    {   // W_out with zero-pad rows up to VPAD
        const float4* s4 = (const float4*)Wout;
        f16x4* h4 = (f16x4*)Wouth;
        f16x4* l4 = (f16x4*)Woutl;
        for (int i = gtid; i < VPAD * HDIM / 4; i += NB * 256) {
            float4 v = (i < VDIM * HDIM / 4) ? s4[i] : make_float4(0.f, 0.f, 0.f, 0.f);
            f16 a = (f16)v.x, b = (f16)v.y, c = (f16)v.z, d = (f16)v.w;
            f16x4 H = {a, b, c, d};
            f16x4 L = {(f16)((v.x - (float)a) * 2048.0f), (f16)((v.y - (float)b) * 2048.0f),
                       (f16)((v.z - (float)c) * 2048.0f), (f16)((v.w - (float)d) * 2048.0f)};
            h4[i] = H;
            l4[i] = L;
        }
    }
    {   // states (exactly one element per thread: 64*1024 == NB*256)
        int i = gtid;
        float a = hidden[i], b = hidden[BDIM * HDIM + i];
        f16 ah = (f16)a, bh = (f16)b;
        h1h[i] = ah; h1l[i] = (f16)((a - (float)ah) * 2048.0f);
        h2h[i] = bh; h2l[i] = (f16)((b - (float)bh) * 2048.0f);
        c1[i] = cellin[i];
        c2[i] = cellin[BDIM * HDIM + i];
    }
    for (int i = gtid; i < BDIM * VDIM; i += NB * 256) {   // out[:,0,:] = one_hot
        int b = i / VDIM, v = i - b * VDIM;
        out[(size_t)b * (TDIM * VDIM) + v] = (v == captions[b * TDIM]) ? 1.0f : 0.0f;
    }
    gridbar(bar);

    // ---------------- prologue: L0 h-gemm for t=1 (KS=4, 256 jobs) ----------------
    {
        int tile = bid >> 2, q = bid & 3;
        gemm_store(h1h, h1l, Whh0h, Whh0l, tile * 64, q * 256, 256,
                   pre0 + q * 262144, 4096);
    }
    gridbar(bar);

    for (int t = 1; t < TDIM; t++) {
        // ---- P1: cell0 (token select + gates + h1 split) ----
        {
            int b = bid >> 2;          // 4 blocks per batch row
            int idx = gtid;
            int i = idx & 1023;
            int tok;
            if (t == 1) {
                tok = captions[b * TDIM];
            } else if (tfmask[t - 1]) {
                tok = captions[b * TDIM + (t - 1)];
            } else {
                // reduce 157 argmax candidates for batch row b (redundant x4 blocks)
                unsigned long long e = (tid < 157) ? cand[(size_t)b * 157 + tid] : 0ull;
                #pragma unroll
                for (int m = 32; m > 0; m >>= 1) {
                    unsigned long long o = __shfl_down(e, m, 64);
                    if (o > e) e = o;
                }
                __shared__ unsigned long long red[4];
                __shared__ int tok_s;
                if ((tid & 63) == 0) red[tid >> 6] = e;
                __syncthreads();
                if (tid == 0) {
                    e = red[0];
                    if (red[1] > e) e = red[1];
                    if (red[2] > e) e = red[2];
                    if (red[3] > e) e = red[3];
                    tok_s = (int)(~(unsigned)(e & 0xffffffffull));
                }
                __syncthreads();
                tok = tok_s;
            }
            float g[4];
            #pragma unroll
            for (int gi = 0; gi < 4; gi++) {
                int j = (gi << 10) + i;
                float s = bih0[j] + bhh0[j] + Wih0[(size_t)j * VDIM + tok];
                #pragma unroll
                for (int q = 0; q < 4; q++) s += pre0[q * 262144 + (b << 12) + j];
                g[gi] = s;
            }
            float ig = sigmoidf_(g[0]), fg = sigmoidf_(g[1]);
            float gg = tanhf(g[2]),     og = sigmoidf_(g[3]);
            float cn = fg * c1[idx] + ig * gg;
            float hn = og * tanhf(cn);
            c1[idx] = cn;
            f16 hh = (f16)hn;
            h1h[idx] = hh;
            h1l[idx] = (f16)((hn - (float)hh) * 2048.0f);
        }
        gridbar(bar);

        // ---- P2: layer-1 GEMMs (z=0: h1@Wih1, z=1: h2@Whh1), KS=2, 256 jobs ----
        {
            int z = bid >> 7, rr = bid & 127;
            int tile = rr >> 1, q = rr & 1;
            const f16* Ah = z ? h2h : h1h;
            const f16* Al = z ? h2l : h1l;
            const f16* Wh = z ? Whh1h : Wih1h;
            const f16* Wl = z ? Whh1l : Wih1l;
            gemm_store(Ah, Al, Wh, Wl, tile * 64, q * 512, 512,
                       pre1 + (z * 2 + q) * 262144, 4096);
        }
        gridbar(bar);

        // ---- P3: cell1 ----
        {
            int b = bid >> 2;
            int idx = gtid;
            int i = idx & 1023;
            float g[4];
            #pragma unroll
            for (int gi = 0; gi < 4; gi++) {
                int j = (gi << 10) + i;
                float s = bih1[j] + bhh1[j];
                #pragma unroll
                for (int q = 0; q < 4; q++) s += pre1[q * 262144 + (b << 12) + j];
                g[gi] = s;
            }
            float ig = sigmoidf_(g[0]), fg = sigmoidf_(g[1]);
            float gg = tanhf(g[2]),     og = sigmoidf_(g[3]);
            float cn = fg * c2[idx] + ig * gg;
            float hn = og * tanhf(cn);
            c2[idx] = cn;
            f16 hh = (f16)hn;
            h2h[idx] = hh;
            h2l[idx] = (f16)((hn - (float)hh) * 2048.0f);
        }
        gridbar(bar);

        // ---- P4: logits GEMM (full-K, direct out + candidates)  ||  L0 gemm(t+1) ----
        if (bid < 157) {
            const int wave = tid >> 6, wr = wave >> 1, wc = wave & 1;
            const int lane = tid & 63, lm = lane & 15, quad = lane >> 4;
            f32x4 acc[2][2] = {};
            f32x4 accL[2][2] = {};
            gemm_frag(h2h, h2l, Wouth, Woutl, wr * 32, bid * 64 + wc * 32, 0, HDIM,
                      acc, accL);
            __shared__ unsigned long long cs[64][2];
            float bo[2];
            #pragma unroll
            for (int ct = 0; ct < 2; ct++) {
                int col = bid * 64 + wc * 32 + ct * 16 + lm;
                bo[ct] = (col < VDIM) ? bout[col] : 0.0f;
            }
            #pragma unroll
            for (int rt = 0; rt < 2; rt++)
                #pragma unroll
                for (int r = 0; r < 4; r++) {
                    int row = wr * 32 + rt * 16 + quad * 4 + r;
                    unsigned long long e = 0ull;
                    #pragma unroll
                    for (int ct = 0; ct < 2; ct++) {
                        int col = bid * 64 + wc * 32 + ct * 16 + lm;
                        if (col < VDIM) {
                            float s = acc[rt][ct][r] + accL[rt][ct][r] * (1.0f / 2048.0f)
                                    + bo[ct];
                            out[(size_t)row * (TDIM * VDIM) + (size_t)t * VDIM + col] = s;
                            unsigned u = __float_as_uint(s);
                            u = (u & 0x80000000u) ? ~u : (u | 0x80000000u);
                            unsigned long long p =
                                ((unsigned long long)u << 32) | (unsigned)(~col);
                            if (p > e) e = p;
                        }
                    }
                    #pragma unroll
                    for (int m = 1; m < 16; m <<= 1) {
                        unsigned long long o = __shfl_xor(e, m, 64);
                        if (o > e) e = o;
                    }
                    if (lm == 0) cs[row][wc] = e;
                }
            __syncthreads();
            if (tid < 64) {
                unsigned long long e = cs[tid][0];
                if (cs[tid][1] > e) e = cs[tid][1];
                cand[(size_t)tid * 157 + bid] = e;
            }
        } else if (t < TDIM - 1) {
            // L0 h-gemm for step t+1 (KS=4, 256 quantum jobs over 99 blocks)
            for (int j = bid - 157; j < 256; j += 99) {
                int tile = j >> 2, q = j & 3;
                gemm_store(h1h, h1l, Whh0h, Whh0l, tile * 64, q * 256, 256,
                           pre0 + q * 262144, 4096);
            }
        }
        gridbar(bar);
    }
}

extern "C" void kernel_launch(void* const* d_in, const int* in_sizes, int n_in,
                              void* d_out, int out_size, void* d_ws, size_t ws_size,
                              hipStream_t stream)
{
    const float* hidden   = (const float*)d_in[0];
    const float* cellin   = (const float*)d_in[1];
    const int*   captions = (const int*)d_in[2];
    const int*   tfmask   = (const int*)d_in[3];
    const float* Wih0 = (const float*)d_in[4];
    const float* Whh0 = (const float*)d_in[5];
    const float* bih0 = (const float*)d_in[6];
    const float* bhh0 = (const float*)d_in[7];
    const float* Wih1 = (const float*)d_in[8];
    const float* Whh1 = (const float*)d_in[9];
    const float* bih1 = (const float*)d_in[10];
    const float* bhh1 = (const float*)d_in[11];
    const float* Wout = (const float*)d_in[12];
    const float* bout = (const float*)d_in[13];

    char* wsb = (char*)d_ws;
    // zero the grid-barrier state (ws is re-poisoned each call)
    hipMemsetAsync(wsb + WS_BAR, 0, 256, stream);
    decode_all<<<NB, 256, 0, stream>>>(hidden, cellin, captions, tfmask,
                                       Wih0, Whh0, bih0, bhh0,
                                       Wih1, Whh1, bih1, bhh1,
                                       Wout, bout, (float*)d_out, wsb);
}